// Round 1
// baseline (544.431 us; speedup 1.0000x reference)
//
#include <hip/hip_runtime.h>
#include <math.h>

#define D 64

__device__ __forceinline__ unsigned enc_f(float f) {
    unsigned u = __float_as_uint(f);
    return (u & 0x80000000u) ? ~u : (u | 0x80000000u);
}
__device__ __forceinline__ float dec_f(unsigned u) {
    return (u & 0x80000000u) ? __uint_as_float(u ^ 0x80000000u) : __uint_as_float(~u);
}
__device__ __forceinline__ float lrelu(float x) { return x >= 0.f ? x : 0.01f * x; }

// ---------------- init: zero output, init segment max/sum ----------------
__global__ void k_init(float* __restrict__ out, int out_n,
                       unsigned* __restrict__ m_u, int nu,
                       unsigned* __restrict__ m_i, int ni,
                       float* __restrict__ s_u, float* __restrict__ s_i) {
    int i = blockIdx.x * blockDim.x + threadIdx.x;
    int stride = gridDim.x * blockDim.x;
    for (int j = i; j < out_n; j += stride) out[j] = 0.f;
    for (int j = i; j < nu; j += stride) { m_u[j] = 0x007FFFFFu; s_u[j] = 0.f; } // enc(-inf)
    for (int j = i; j < ni; j += stride) { m_i[j] = 0x007FFFFFu; s_i[j] = 0.f; }
}

// ---------------- per-node GEMVs (X@Wsrc+bsrc, 0.5*(X@Wdst+bdst), X@Wo+bo, P@Wu+bu) ----
__global__ __launch_bounds__(256, 1) void k_nodes(
    const float* __restrict__ X, const float* __restrict__ P,
    const float* __restrict__ Wsrc, const float* __restrict__ bsrc,
    const float* __restrict__ Wdst, const float* __restrict__ bdst,
    const float* __restrict__ Wo,   const float* __restrict__ bo,
    const float* __restrict__ Wu,   const float* __restrict__ bu,
    float* __restrict__ out_hs, float* __restrict__ out_hd,
    float* __restrict__ out_ho, float* __restrict__ out_pw,
    int n, int npb) {
    __shared__ float sW[4][D * D];      // 64 KB
    __shared__ float sx[4][D], sp[4][D];
    int tid = threadIdx.x;
    for (int t = tid; t < D * D; t += 256) {
        sW[0][t] = Wsrc[t];
        sW[1][t] = Wdst[t];
        sW[2][t] = Wo[t];
        sW[3][t] = Wu[t];
    }
    int lane = tid & 63, g = tid >> 6;
    int base = blockIdx.x * npb;
    float bs = bsrc[lane], bd = bdst[lane], bo_ = bo[lane], bu_ = bu[lane];
    for (int off = 0; off < npb; off += 4) {
        int node = base + off + g;
        bool act = node < n;
        __syncthreads();
        if (act) {
            sx[g][lane] = X[node * D + lane];
            sp[g][lane] = P[node * D + lane];
        }
        __syncthreads();
        if (act) {
            float a0 = 0.f, a1 = 0.f, a2 = 0.f, a3 = 0.f;
#pragma unroll 8
            for (int k = 0; k < D; ++k) {
                float xk = sx[g][k], pk = sp[g][k];
                a0 += xk * sW[0][k * D + lane];
                a1 += xk * sW[1][k * D + lane];
                a2 += xk * sW[2][k * D + lane];
                a3 += pk * sW[3][k * D + lane];
            }
            out_hs[node * D + lane] = a0 + bs;
            out_hd[node * D + lane] = 0.5f * (a1 + bd);
            out_ho[node * D + lane] = a2 + bo_;
            out_pw[node * D + lane] = a3 + bu_;
        }
    }
}

// ---------------- pass 1: per-review attention weights + logits + segment max ----
__global__ __launch_bounds__(256, 1) void k_rev1(
    const int* __restrict__ ru, const int* __restrict__ ri,
    const float* __restrict__ hsu, const float* __restrict__ hsi,
    const float* __restrict__ hdu, const float* __restrict__ hdi,
    const float* __restrict__ hou, const float* __restrict__ hoi,
    const float* __restrict__ pwu, const float* __restrict__ pwi,
    const float* __restrict__ watt_rep, const float* __restrict__ batt_rep,
    const float* __restrict__ watt_agg, const float* __restrict__ batt_agg,
    float* __restrict__ w_u, float* __restrict__ a_ul, float* __restrict__ a_il,
    unsigned* __restrict__ m_user, unsigned* __restrict__ m_item, int R) {
    int lane = threadIdx.x & 63;
    int r = blockIdx.x * 4 + (threadIdx.x >> 6);
    if (r >= R) return;
    int u = ru[r], it = ri[r];
    float wr = watt_rep[lane], wa = watt_agg[lane];
    float hd = hdu[(size_t)u * D + lane] + hdi[(size_t)it * D + lane];
    float tu = lrelu(hsu[(size_t)u * D + lane] + hd) * wr;
    float ti = lrelu(hsi[(size_t)it * D + lane] + hd) * wr;
#pragma unroll
    for (int o = 32; o; o >>= 1) {
        tu += __shfl_xor(tu, o, 64);
        ti += __shfl_xor(ti, o, 64);
    }
    float br = batt_rep[0];
    float a_u = expf(tu + br), a_i = expf(ti + br);
    float inv = 1.f / (a_u + a_i);
    float wu = a_u * inv, wi = a_i * inv;
    float ho = wu * hou[(size_t)u * D + lane] + wi * hoi[(size_t)it * D + lane];
    float zu = lrelu(ho + pwi[(size_t)it * D + lane]) * wa;  // user-side: pref_item emb
    float zi = lrelu(ho + pwu[(size_t)u * D + lane]) * wa;   // item-side: pref_user emb
#pragma unroll
    for (int o = 32; o; o >>= 1) {
        zu += __shfl_xor(zu, o, 64);
        zi += __shfl_xor(zi, o, 64);
    }
    float ba = batt_agg[0];
    if (lane == 0) {
        float aul = zu + ba, ail = zi + ba;
        w_u[r] = wu;
        a_ul[r] = aul;
        a_il[r] = ail;
        atomicMax(&m_user[u], enc_f(aul));
        atomicMax(&m_item[it], enc_f(ail));
    }
}

// ---------------- pass 2: e = exp(a - m[dst]); segment sums ----------------
__global__ void k_rev2(const int* __restrict__ ru, const int* __restrict__ ri,
                       const float* __restrict__ a_ul, const float* __restrict__ a_il,
                       const unsigned* __restrict__ m_user, const unsigned* __restrict__ m_item,
                       float* __restrict__ e_u, float* __restrict__ e_i,
                       float* __restrict__ s_user, float* __restrict__ s_item, int R) {
    int r = blockIdx.x * blockDim.x + threadIdx.x;
    if (r >= R) return;
    int u = ru[r], it = ri[r];
    float eu = expf(a_ul[r] - dec_f(m_user[u]));
    float ei = expf(a_il[r] - dec_f(m_item[it]));
    e_u[r] = eu;
    e_i[r] = ei;
    atomicAdd(&s_user[u], eu);
    atomicAdd(&s_item[it], ei);
}

// ---------------- pass 3: h_rev scatter-add into both outputs ----------------
__global__ __launch_bounds__(256, 1) void k_rev3(
    const int* __restrict__ ru, const int* __restrict__ ri,
    const float* __restrict__ Xu, const float* __restrict__ Xi,
    const float* __restrict__ w_u,
    const float* __restrict__ e_u, const float* __restrict__ e_i,
    const float* __restrict__ s_user, const float* __restrict__ s_item,
    float* __restrict__ out, int nu, int R) {
    int lane = threadIdx.x & 63;
    int r = blockIdx.x * 4 + (threadIdx.x >> 6);
    if (r >= R) return;
    int u = ru[r], it = ri[r];
    float wu = w_u[r], wi = 1.f - wu;
    float h = wu * Xu[(size_t)u * D + lane] + wi * Xi[(size_t)it * D + lane];
    float wuser = e_u[r] / s_user[u];
    float witem = e_i[r] / s_item[it];
    atomicAdd(&out[(size_t)u * D + lane], wuser * h);
    atomicAdd(&out[((size_t)nu + it) * D + lane], witem * h);
}

extern "C" void kernel_launch(void* const* d_in, const int* in_sizes, int n_in,
                              void* d_out, int out_size, void* d_ws, size_t ws_size,
                              hipStream_t stream) {
    const float* Xu        = (const float*)d_in[0];
    const float* Xi        = (const float*)d_in[1];
    const float* Wsrc      = (const float*)d_in[2];
    const float* bsrc      = (const float*)d_in[3];
    const float* Wdst      = (const float*)d_in[4];
    const float* bdst      = (const float*)d_in[5];
    const float* watt_rep  = (const float*)d_in[6];
    const float* batt_rep  = (const float*)d_in[7];
    const float* Wo        = (const float*)d_in[8];
    const float* bo        = (const float*)d_in[9];
    const float* Wu        = (const float*)d_in[10];
    const float* bu        = (const float*)d_in[11];
    const float* watt_agg  = (const float*)d_in[12];
    const float* batt_agg  = (const float*)d_in[13];
    const float* pref_user = (const float*)d_in[14];
    const float* pref_item = (const float*)d_in[15];
    const int* r_user      = (const int*)d_in[16];
    const int* r_item      = (const int*)d_in[17];

    int nu = in_sizes[0] / D;
    int ni = in_sizes[1] / D;
    int R  = in_sizes[16];

    float* ws = (float*)d_ws;
    size_t off = 0;
    float* hsu = ws + off; off += (size_t)nu * D;
    float* hsi = ws + off; off += (size_t)ni * D;
    float* hdu = ws + off; off += (size_t)nu * D;
    float* hdi = ws + off; off += (size_t)ni * D;
    float* hou = ws + off; off += (size_t)nu * D;
    float* hoi = ws + off; off += (size_t)ni * D;
    float* pwu = ws + off; off += (size_t)nu * D;
    float* pwi = ws + off; off += (size_t)ni * D;
    float* w_u  = ws + off; off += (size_t)R;
    float* a_ul = ws + off; off += (size_t)R;
    float* a_il = ws + off; off += (size_t)R;
    float* e_u  = ws + off; off += (size_t)R;
    float* e_i  = ws + off; off += (size_t)R;
    unsigned* m_user = (unsigned*)(ws + off); off += (size_t)nu;
    unsigned* m_item = (unsigned*)(ws + off); off += (size_t)ni;
    float* s_user = ws + off; off += (size_t)nu;
    float* s_item = ws + off; off += (size_t)ni;

    int out_n = (nu + ni) * D;

    // init
    k_init<<<2048, 256, 0, stream>>>(
        (float*)d_out, out_n, m_user, nu, m_item, ni, s_user, s_item);

    // node-level precompute (user domain, item domain)
    const int NPB = 96;
    k_nodes<<<(nu + NPB - 1) / NPB, 256, 0, stream>>>(
        Xu, pref_user, Wsrc, bsrc, Wdst, bdst, Wo, bo, Wu, bu,
        hsu, hdu, hou, pwu, nu, NPB);
    k_nodes<<<(ni + NPB - 1) / NPB, 256, 0, stream>>>(
        Xi, pref_item, Wsrc, bsrc, Wdst, bdst, Wo, bo, Wu, bu,
        hsi, hdi, hoi, pwi, ni, NPB);

    // review pass 1: weights + logits + segment max
    k_rev1<<<(R + 3) / 4, 256, 0, stream>>>(
        r_user, r_item, hsu, hsi, hdu, hdi, hou, hoi, pwu, pwi,
        watt_rep, batt_rep, watt_agg, batt_agg,
        w_u, a_ul, a_il, m_user, m_item, R);

    // review pass 2: exp + segment sum
    k_rev2<<<(R + 255) / 256, 256, 0, stream>>>(
        r_user, r_item, a_ul, a_il, m_user, m_item, e_u, e_i, s_user, s_item, R);

    // review pass 3: weighted scatter into output
    k_rev3<<<(R + 3) / 4, 256, 0, stream>>>(
        r_user, r_item, Xu, Xi, w_u, e_u, e_i, s_user, s_item,
        (float*)d_out, nu, R);
}